// Round 1
// baseline (478.334 us; speedup 1.0000x reference)
//
#include <hip/hip_runtime.h>

#define B_ 2
#define C_ 256
#define H_ 56
#define W_ 56
#define N_ 64
#define M_ 8
#define P_ 7
#define R_ (N_ + N_*M_)          // 576 rois per image
#define BR_ (B_*R_)              // 1152
#define K_ 12                    // max y-window taps (bin<=7.92 -> support<=10)

// ---- workspace layout (float-element offsets) ----
#define F_FMT 0
#define N_FMT (B_*H_*W_*C_)                  // 1,605,632  channel-last feature map
#define F_WY  (F_FMT + N_FMT)
#define N_WY  (BR_*P_*K_)                    // 96,768     windowed y-weights
#define F_AXD (F_WY + N_WY)
#define N_AXD (BR_*W_*P_)                    // 451,584    dense-in-x weights [x][px]
#define E_YB  (F_AXD + N_AXD)                // int region (aliased): ybase [BR][7]
#define E_YL  (E_YB + BR_*P_)                //                        ylen  [BR][7]
#define E_XLO (E_YL + BR_*P_)                //                        xlo   [BR]
#define E_XHI (E_XLO + BR_)                  //                        xhi   [BR]
#define WS_ELEMS (E_XHI + BR_)               // ~8.7 MB total

// ---------------------------------------------------------------------------
// Pass 0: fm[b][c][y][x] -> fmt[b][y][x][c]  (channel-last for coalesced lanes)
// grid = B*H*4 blocks of 64 threads; thread = one channel, loops x with float4
__global__ void k_transpose(const float* __restrict__ fm, float* __restrict__ fmt) {
    int bid = blockIdx.x;
    int cg  = bid & 3;
    int y   = (bid >> 2) % H_;
    int b   = bid / (4 * H_);
    int c   = cg * 64 + (int)threadIdx.x;
    const float4* src = (const float4*)(fm + (((size_t)b * C_ + c) * H_ + y) * W_);
    float* dst = fmt + ((size_t)b * H_ + y) * (size_t)(W_ * C_) + c;
#pragma unroll
    for (int x4 = 0; x4 < W_ / 4; ++x4) {
        float4 v = src[x4];
        dst[(x4 * 4 + 0) * C_] = v.x;
        dst[(x4 * 4 + 1) * C_] = v.y;
        dst[(x4 * 4 + 2) * C_] = v.z;
        dst[(x4 * 4 + 3) * C_] = v.w;
    }
}

// ---------------------------------------------------------------------------
// Pass 1: per-(b,roi,p) axis weights. y: windowed [base,len,12 taps].
//         x: dense transposed axd[x][px] via atomicAdd (region pre-zeroed).
__global__ void k_weights(const float* __restrict__ boxes,
                          const float* __restrict__ gt,
                          float* __restrict__ ws_f) {
    __shared__ float sw[256][K_];
    int tid = blockIdx.x * 256 + threadIdx.x;
    if (tid >= BR_ * P_) return;
    int p  = tid % P_;
    int br = tid / P_;
    int r  = br % R_;
    int b  = br / R_;
    int* ip = (int*)ws_f;

    float x1, y1, x2, y2;
    if (r < N_) {
        const float* bp = boxes + ((size_t)b * N_ + r) * 4;
        x1 = bp[0]; y1 = bp[1]; x2 = bp[2]; y2 = bp[3];
    } else {
        int q = r - N_;
        int n = q / M_, m = q % M_;
        const float* bp = boxes + ((size_t)b * N_ + n) * 4;
        const float* gp = gt + ((size_t)b * M_ + m) * 4;
        x1 = fminf(bp[0], gp[0]); y1 = fminf(bp[1], gp[1]);
        x2 = fmaxf(bp[2], gp[2]); y2 = fmaxf(bp[3], gp[3]);
    }
    float rw = fmaxf(x2 - x1, 1.0f);
    float rh = fmaxf(y2 - y1, 1.0f);

    // ---- y axis: windowed ----
    {
        float bin = rh / 7.0f;
        float gf  = ceilf(bin);
        int   g   = (int)gf;
        float ivg = 1.0f / gf;
        float start = y1 + (float)p * bin;
        int base = (int)floorf(fmaxf(start, 0.0f));
        base = min(max(base, 0), H_ - 1);
        float* swp = &sw[threadIdx.x][0];
#pragma unroll
        for (int k = 0; k < K_; ++k) swp[k] = 0.0f;
        int len = 0;
        for (int s = 0; s < g; ++s) {
            float coord = start + ((float)s + 0.5f) * bin * ivg;
            if (coord < -1.0f || coord > (float)H_) continue;
            float cc = fmaxf(coord, 0.0f);
            int low = (int)floorf(cc);
            int high; float l;
            if (low >= H_ - 1) { low = H_ - 1; high = H_ - 1; l = 0.0f; }
            else               { high = low + 1; l = cc - (float)low; }
            int kl = min(max(low - base, 0), K_ - 1);
            int kh = min(max(high - base, 0), K_ - 1);
            swp[kl] += (1.0f - l) * ivg;
            swp[kh] += l * ivg;
            len = max(len, kh + 1);
        }
        float* wyp = ws_f + F_WY + (size_t)br * (P_ * K_) + p * K_;
#pragma unroll
        for (int k = 0; k < K_; ++k) wyp[k] = swp[k];
        ip[E_YB + br * P_ + p] = base;
        ip[E_YL + br * P_ + p] = len;
    }

    // ---- x axis: dense transposed scatter ----
    {
        float bin = rw / 7.0f;
        float gf  = ceilf(bin);
        int   g   = (int)gf;
        float ivg = 1.0f / gf;
        float start = x1 + (float)p * bin;
        float* axp = ws_f + F_AXD + (size_t)br * (W_ * P_);
        for (int s = 0; s < g; ++s) {
            float coord = start + ((float)s + 0.5f) * bin * ivg;
            if (coord < -1.0f || coord > (float)W_) continue;
            float cc = fmaxf(coord, 0.0f);
            int low = (int)floorf(cc);
            int high; float l;
            if (low >= W_ - 1) { low = W_ - 1; high = W_ - 1; l = 0.0f; }
            else               { high = low + 1; l = cc - (float)low; }
            atomicAdd(&axp[low * P_ + p],  (1.0f - l) * ivg);
            atomicAdd(&axp[high * P_ + p], l * ivg);
        }
        if (p == 0) {
            ip[E_XLO + br] = min(max((int)floorf(fmaxf(x1, 0.0f)), 0), W_ - 1);
            ip[E_XHI + br] = min(max((int)floorf(x1 + rw) + 1, 0), W_ - 1) + 1;
        }
    }
}

// ---------------------------------------------------------------------------
// Pass 2: block = (b, n, 64-ch group); 256 thr = 64 ch x 4 roi-groups.
// Roi-group rg handles rois k = rg, rg+4, rg+8 (k=0 box, k>=1 ctx m=k-1, x1/8).
// Per roi: stream x columns; colsum[py] via windowed y taps (lane=channel ->
// coalesced 256B loads); rank-1 update of 49 accs via dense axd (zero-skip).
__global__ __launch_bounds__(256) void k_main(const float* __restrict__ ws_f,
                                              float* __restrict__ out) {
    __shared__ float lds_red[4 * 64 * 49];   // 50,176 B
    __shared__ float lds_wy[4][P_ * K_];     //  1,344 B
    __shared__ float lds_ax[4][W_ * P_];     //  6,272 B

    const int* ip = (const int*)ws_f;
    int bid  = blockIdx.x;
    int cg   = bid & 3;
    int n    = (bid >> 2) & (N_ - 1);
    int b    = bid >> 8;
    int lane = threadIdx.x & 63;
    int rg   = threadIdx.x >> 6;
    int c    = cg * 64 + lane;

    const float* fmtb = ws_f + F_FMT + (size_t)b * (H_ * W_ * C_);

    float acc[49];
#pragma unroll
    for (int q = 0; q < 49; ++q) acc[q] = 0.0f;

    for (int kk = 0; kk < 3; ++kk) {        // fixed trip count -> barriers legal
        int k = kk * 4 + rg;
        bool active = (k < 9);
        __syncthreads();                    // protect prior iter's LDS reads
        int br = 0; float scale = 1.0f;
        if (active) {
            int r = (k == 0) ? n : (N_ + n * M_ + (k - 1));
            br = b * R_ + r;
            scale = (k == 0) ? 1.0f : (1.0f / (float)M_);
            const float* wyp = ws_f + F_WY + (size_t)br * (P_ * K_);
            lds_wy[rg][lane] = wyp[lane];
            if (lane < P_ * K_ - 64) lds_wy[rg][64 + lane] = wyp[64 + lane];
            const float* axp = ws_f + F_AXD + (size_t)br * (W_ * P_);
            for (int j = lane; j < W_ * P_; j += 64) lds_ax[rg][j] = axp[j];
        }
        __syncthreads();
        if (!active) continue;

        int yb[P_], yl[P_];
#pragma unroll
        for (int py = 0; py < P_; ++py) {
            yb[py] = ip[E_YB + br * P_ + py];
            yl[py] = ip[E_YL + br * P_ + py];
        }
        int xlo = ip[E_XLO + br];
        int xhi = ip[E_XHI + br];
        const float* lwy = &lds_wy[rg][0];
        const float* lax = &lds_ax[rg][0];

        for (int x = xlo; x < xhi; x += 2) {
            bool two = (x + 1 < xhi);
            float cs0[P_], cs1[P_];
#pragma unroll
            for (int py = 0; py < P_; ++py) {
                float s0 = 0.0f, s1 = 0.0f;
                int off = (yb[py] * W_ + x) * C_ + c;
                int L = yl[py];
                for (int i = 0; i < L; ++i) {
                    float wv = lwy[py * K_ + i];
                    s0 = fmaf(wv, fmtb[off], s0);
                    s1 = fmaf(wv, fmtb[off + C_], s1);   // may read 1 col past
                    off += W_ * C_;                       // window; in-ws, unused
                }
                cs0[py] = s0; cs1[py] = s1;
            }
#pragma unroll
            for (int px = 0; px < P_; ++px) {
                float w = lax[x * P_ + px];
                if (w != 0.0f) {
                    w *= scale;
#pragma unroll
                    for (int py = 0; py < P_; ++py)
                        acc[py * P_ + px] = fmaf(w, cs0[py], acc[py * P_ + px]);
                }
            }
            if (two) {
#pragma unroll
                for (int px = 0; px < P_; ++px) {
                    float w = lax[(x + 1) * P_ + px];
                    if (w != 0.0f) {
                        w *= scale;
#pragma unroll
                        for (int py = 0; py < P_; ++py)
                            acc[py * P_ + px] = fmaf(w, cs1[py], acc[py * P_ + px]);
                    }
                }
            }
        }
    }

    // ---- reduce the 4 roi-group partials, write coalesced ----
    __syncthreads();
#pragma unroll
    for (int q = 0; q < 49; ++q) lds_red[(rg * 64 + lane) * 49 + q] = acc[q];
    __syncthreads();
    float* outp = out + (((size_t)b * N_ + n) * C_ + cg * 64) * 49;
    for (int e = (int)threadIdx.x; e < 64 * 49; e += 256) {
        float v = lds_red[e] + lds_red[3136 + e] + lds_red[2 * 3136 + e] +
                  lds_red[3 * 3136 + e];
        outp[e] = v;
    }
}

// ---------------------------------------------------------------------------
extern "C" void kernel_launch(void* const* d_in, const int* in_sizes, int n_in,
                              void* d_out, int out_size, void* d_ws, size_t ws_size,
                              hipStream_t stream) {
    const float* fm    = (const float*)d_in[0];
    const float* boxes = (const float*)d_in[1];
    const float* gt    = (const float*)d_in[2];
    float* ws_f = (float*)d_ws;
    float* out  = (float*)d_out;

    // axd region is scatter-accumulated -> must be zeroed every launch
    hipMemsetAsync(ws_f + F_AXD, 0, (size_t)N_AXD * sizeof(float), stream);
    k_transpose<<<B_ * H_ * 4, 64, 0, stream>>>(fm, ws_f + F_FMT);
    k_weights<<<(BR_ * P_ + 255) / 256, 256, 0, stream>>>(boxes, gt, ws_f);
    k_main<<<B_ * N_ * 4, 256, 0, stream>>>(ws_f, out);
}

// Round 2
// 308.496 us; speedup vs baseline: 1.5505x; 1.5505x over previous
//
#include <hip/hip_runtime.h>

#define B_ 2
#define C_ 256
#define H_ 56
#define W_ 56
#define N_ 64
#define M_ 8
#define P_ 7
#define R_ (N_ + N_*M_)          // 576 rois per image
#define BR_ (B_*R_)              // 1152
#define K_ 12                    // max y-window taps (bin<=7.92 -> support<=10)

// ---- workspace layout (float-element offsets) ----
#define F_FMT 0
#define N_FMT (B_*H_*W_*C_)                  // 1,605,632  channel-last feature map
#define F_WY  (F_FMT + N_FMT)
#define N_WY  (BR_*P_*K_)                    // 96,768     windowed y-weights
#define F_AXD (F_WY + N_WY)
#define N_AXD (BR_*W_*P_)                    // 451,584    dense-in-x weights [x][px]
#define E_YB  (F_AXD + N_AXD)                // int region (aliased): ybase [BR][7]
#define E_YL  (E_YB + BR_*P_)                //                        ylen  [BR][7]
#define E_XLO (E_YL + BR_*P_)                //                        xlo   [BR]
#define E_XHI (E_XLO + BR_)                  //                        xhi   [BR]
#define WS_ELEMS (E_XHI + BR_)               // ~8.7 MB total

// ---------------------------------------------------------------------------
// Pass 0: fm[b][c][y][x] -> fmt[b][y][x][c]  (channel-last for coalesced lanes)
__global__ void k_transpose(const float* __restrict__ fm, float* __restrict__ fmt) {
    int bid = blockIdx.x;
    int cg  = bid & 3;
    int y   = (bid >> 2) % H_;
    int b   = bid / (4 * H_);
    int c   = cg * 64 + (int)threadIdx.x;
    const float4* src = (const float4*)(fm + (((size_t)b * C_ + c) * H_ + y) * W_);
    float* dst = fmt + ((size_t)b * H_ + y) * (size_t)(W_ * C_) + c;
#pragma unroll
    for (int x4 = 0; x4 < W_ / 4; ++x4) {
        float4 v = src[x4];
        dst[(x4 * 4 + 0) * C_] = v.x;
        dst[(x4 * 4 + 1) * C_] = v.y;
        dst[(x4 * 4 + 2) * C_] = v.z;
        dst[(x4 * 4 + 3) * C_] = v.w;
    }
}

// ---------------------------------------------------------------------------
// Pass 1: per-(b,roi,p) axis weights (unchanged from R1 — verified correct).
__global__ void k_weights(const float* __restrict__ boxes,
                          const float* __restrict__ gt,
                          float* __restrict__ ws_f) {
    __shared__ float sw[256][K_];
    int tid = blockIdx.x * 256 + threadIdx.x;
    if (tid >= BR_ * P_) return;
    int p  = tid % P_;
    int br = tid / P_;
    int r  = br % R_;
    int b  = br / R_;
    int* ip = (int*)ws_f;

    float x1, y1, x2, y2;
    if (r < N_) {
        const float* bp = boxes + ((size_t)b * N_ + r) * 4;
        x1 = bp[0]; y1 = bp[1]; x2 = bp[2]; y2 = bp[3];
    } else {
        int q = r - N_;
        int n = q / M_, m = q % M_;
        const float* bp = boxes + ((size_t)b * N_ + n) * 4;
        const float* gp = gt + ((size_t)b * M_ + m) * 4;
        x1 = fminf(bp[0], gp[0]); y1 = fminf(bp[1], gp[1]);
        x2 = fmaxf(bp[2], gp[2]); y2 = fmaxf(bp[3], gp[3]);
    }
    float rw = fmaxf(x2 - x1, 1.0f);
    float rh = fmaxf(y2 - y1, 1.0f);

    {   // y axis: windowed
        float bin = rh / 7.0f;
        float gf  = ceilf(bin);
        int   g   = (int)gf;
        float ivg = 1.0f / gf;
        float start = y1 + (float)p * bin;
        int base = (int)floorf(fmaxf(start, 0.0f));
        base = min(max(base, 0), H_ - 1);
        float* swp = &sw[threadIdx.x][0];
#pragma unroll
        for (int k = 0; k < K_; ++k) swp[k] = 0.0f;
        int len = 0;
        for (int s = 0; s < g; ++s) {
            float coord = start + ((float)s + 0.5f) * bin * ivg;
            if (coord < -1.0f || coord > (float)H_) continue;
            float cc = fmaxf(coord, 0.0f);
            int low = (int)floorf(cc);
            int high; float l;
            if (low >= H_ - 1) { low = H_ - 1; high = H_ - 1; l = 0.0f; }
            else               { high = low + 1; l = cc - (float)low; }
            int kl = min(max(low - base, 0), K_ - 1);
            int kh = min(max(high - base, 0), K_ - 1);
            swp[kl] += (1.0f - l) * ivg;
            swp[kh] += l * ivg;
            len = max(len, kh + 1);
        }
        float* wyp = ws_f + F_WY + (size_t)br * (P_ * K_) + p * K_;
#pragma unroll
        for (int k = 0; k < K_; ++k) wyp[k] = swp[k];
        ip[E_YB + br * P_ + p] = base;
        ip[E_YL + br * P_ + p] = len;
    }

    {   // x axis: dense transposed scatter
        float bin = rw / 7.0f;
        float gf  = ceilf(bin);
        int   g   = (int)gf;
        float ivg = 1.0f / gf;
        float start = x1 + (float)p * bin;
        float* axp = ws_f + F_AXD + (size_t)br * (W_ * P_);
        for (int s = 0; s < g; ++s) {
            float coord = start + ((float)s + 0.5f) * bin * ivg;
            if (coord < -1.0f || coord > (float)W_) continue;
            float cc = fmaxf(coord, 0.0f);
            int low = (int)floorf(cc);
            int high; float l;
            if (low >= W_ - 1) { low = W_ - 1; high = W_ - 1; l = 0.0f; }
            else               { high = low + 1; l = cc - (float)low; }
            atomicAdd(&axp[low * P_ + p],  (1.0f - l) * ivg);
            atomicAdd(&axp[high * P_ + p], l * ivg);
        }
        if (p == 0) {
            ip[E_XLO + br] = min(max((int)floorf(fmaxf(x1, 0.0f)), 0), W_ - 1);
            ip[E_XHI + br] = min(max((int)floorf(x1 + rw) + 1, 0), W_ - 1) + 1;
        }
    }
}

// ---------------------------------------------------------------------------
// Pass 2: one wave per (b, n, roi k, 64-ch group). Grid = 2*64*9*4 = 4608.
// acc is additive across rois -> each block computes its roi's contribution
// (scaled) and atomicAdds into d_out (zeroed each launch). LDS transpose
// makes the atomics fully coalesced (49 x 256B wave-atomics per block).
__global__ __launch_bounds__(64) void k_main(const float* __restrict__ ws_f,
                                             float* __restrict__ out) {
    __shared__ float lds_wy[P_ * K_];    //    336 B
    __shared__ float lds_ax[W_ * P_];    //  1,568 B
    __shared__ float lds_red[64 * 49];   // 12,544 B  -> ~11 blocks/CU

    const int* ip = (const int*)ws_f;
    int bid  = blockIdx.x;
    int cg   = bid & 3;
    int k    = (bid >> 2) % 9;
    int n    = (bid / 36) & (N_ - 1);
    int b    = bid / (36 * N_);
    int lane = (int)threadIdx.x;
    int c    = cg * 64 + lane;

    int r  = (k == 0) ? n : (N_ + n * M_ + (k - 1));
    int br = b * R_ + r;
    float scale = (k == 0) ? 1.0f : (1.0f / (float)M_);

    // stage this roi's weights into LDS
    const float* wyp = ws_f + F_WY + (size_t)br * (P_ * K_);
    for (int j = lane; j < P_ * K_; j += 64) lds_wy[j] = wyp[j];
    const float* axp = ws_f + F_AXD + (size_t)br * (W_ * P_);
    for (int j = lane; j < W_ * P_; j += 64) lds_ax[j] = axp[j];
    __syncthreads();

    int yb[P_], yl[P_];
#pragma unroll
    for (int py = 0; py < P_; ++py) {
        yb[py] = ip[E_YB + br * P_ + py];
        yl[py] = ip[E_YL + br * P_ + py];
    }
    int xlo = ip[E_XLO + br];
    int xhi = ip[E_XHI + br];

    const float* fmtb = ws_f + F_FMT + (size_t)b * (H_ * W_ * C_);

    float acc[49];
#pragma unroll
    for (int q = 0; q < 49; ++q) acc[q] = 0.0f;

    for (int x = xlo; x < xhi; x += 2) {
        bool two = (x + 1 < xhi);
        float cs0[P_], cs1[P_];
#pragma unroll
        for (int py = 0; py < P_; ++py) {
            float s0 = 0.0f, s1 = 0.0f;
            int off = (yb[py] * W_ + x) * C_ + c;
            int L = yl[py];
            for (int i = 0; i < L; ++i) {
                float wv = lds_wy[py * K_ + i];
                s0 = fmaf(wv, fmtb[off], s0);
                s1 = fmaf(wv, fmtb[off + C_], s1);   // x+1 col; stays in-ws
                off += W_ * C_;
            }
            cs0[py] = s0; cs1[py] = s1;
        }
#pragma unroll
        for (int px = 0; px < P_; ++px) {
            float w = lds_ax[x * P_ + px];
            if (w != 0.0f) {                          // wave-uniform branch
                w *= scale;
#pragma unroll
                for (int py = 0; py < P_; ++py)
                    acc[py * P_ + px] = fmaf(w, cs0[py], acc[py * P_ + px]);
            }
        }
        if (two) {
#pragma unroll
            for (int px = 0; px < P_; ++px) {
                float w = lds_ax[(x + 1) * P_ + px];
                if (w != 0.0f) {
                    w *= scale;
#pragma unroll
                    for (int py = 0; py < P_; ++py)
                        acc[py * P_ + px] = fmaf(w, cs1[py], acc[py * P_ + px]);
                }
            }
        }
    }

    // ---- transpose through LDS, coalesced atomic epilogue ----
    __syncthreads();
#pragma unroll
    for (int q = 0; q < 49; ++q) lds_red[lane * 49 + q] = acc[q];  // 49 odd -> conflict-free
    __syncthreads();
    float* outp = out + (((size_t)b * N_ + n) * C_ + cg * 64) * 49;
    for (int e = lane; e < 64 * 49; e += 64)
        atomicAdd(&outp[e], lds_red[e]);
}

// ---------------------------------------------------------------------------
extern "C" void kernel_launch(void* const* d_in, const int* in_sizes, int n_in,
                              void* d_out, int out_size, void* d_ws, size_t ws_size,
                              hipStream_t stream) {
    const float* fm    = (const float*)d_in[0];
    const float* boxes = (const float*)d_in[1];
    const float* gt    = (const float*)d_in[2];
    float* ws_f = (float*)d_ws;
    float* out  = (float*)d_out;

    // axd is scatter-accumulated and out is atomic-accumulated -> zero both
    hipMemsetAsync(ws_f + F_AXD, 0, (size_t)N_AXD * sizeof(float), stream);
    hipMemsetAsync(out, 0, (size_t)out_size * sizeof(float), stream);
    k_transpose<<<B_ * H_ * 4, 64, 0, stream>>>(fm, ws_f + F_FMT);
    k_weights<<<(BR_ * P_ + 255) / 256, 256, 0, stream>>>(boxes, gt, ws_f);
    k_main<<<B_ * N_ * 9 * 4, 64, 0, stream>>>(ws_f, out);
}

// Round 3
// 282.908 us; speedup vs baseline: 1.6908x; 1.0904x over previous
//
#include <hip/hip_runtime.h>

#define B_ 2
#define C_ 256
#define H_ 56
#define W_ 56
#define N_ 64
#define M_ 8
#define P_ 7
#define R_ (N_ + N_*M_)          // 576 rois per image
#define BR_ (B_*R_)              // 1152
#define K_ 12                    // max y-window taps (bin<=7.92 -> support<=10)

// ---- workspace layout (float-element offsets) ----
#define F_FMT 0
#define N_FMT (B_*H_*W_*C_)                  // 1,605,632  channel-last feature map
#define F_WY  (F_FMT + N_FMT)
#define N_WY  (BR_*P_*K_)                    // 96,768     windowed y-weights
#define F_AXD (F_WY + N_WY)
#define N_AXD (BR_*W_*P_)                    // 451,584    dense-in-x weights [x][px]
#define E_YB  (F_AXD + N_AXD)                // int region (aliased): ybase [BR][7]
#define E_YL  (E_YB + BR_*P_)                //                        ylen  [BR][7]
#define E_XLO (E_YL + BR_*P_)                //                        xlo   [BR]
#define E_XHI (E_XLO + BR_)                  //                        xhi   [BR]
#define WS_ELEMS (E_XHI + BR_)               // ~8.7 MB total

// ---------------------------------------------------------------------------
// Pass 0: fm[b][c][y][x] -> fmt[b][y][x][c]  (channel-last for coalesced lanes)
__global__ void k_transpose(const float* __restrict__ fm, float* __restrict__ fmt) {
    int bid = blockIdx.x;
    int cg  = bid & 3;
    int y   = (bid >> 2) % H_;
    int b   = bid / (4 * H_);
    int c   = cg * 64 + (int)threadIdx.x;
    const float4* src = (const float4*)(fm + (((size_t)b * C_ + c) * H_ + y) * W_);
    float* dst = fmt + ((size_t)b * H_ + y) * (size_t)(W_ * C_) + c;
#pragma unroll
    for (int x4 = 0; x4 < W_ / 4; ++x4) {
        float4 v = src[x4];
        dst[(x4 * 4 + 0) * C_] = v.x;
        dst[(x4 * 4 + 1) * C_] = v.y;
        dst[(x4 * 4 + 2) * C_] = v.z;
        dst[(x4 * 4 + 3) * C_] = v.w;
    }
}

// ---------------------------------------------------------------------------
// Pass 1: per-(b,roi,p) axis weights (unchanged — verified correct since R1).
__global__ void k_weights(const float* __restrict__ boxes,
                          const float* __restrict__ gt,
                          float* __restrict__ ws_f) {
    __shared__ float sw[256][K_];
    int tid = blockIdx.x * 256 + threadIdx.x;
    if (tid >= BR_ * P_) return;
    int p  = tid % P_;
    int br = tid / P_;
    int r  = br % R_;
    int b  = br / R_;
    int* ip = (int*)ws_f;

    float x1, y1, x2, y2;
    if (r < N_) {
        const float* bp = boxes + ((size_t)b * N_ + r) * 4;
        x1 = bp[0]; y1 = bp[1]; x2 = bp[2]; y2 = bp[3];
    } else {
        int q = r - N_;
        int n = q / M_, m = q % M_;
        const float* bp = boxes + ((size_t)b * N_ + n) * 4;
        const float* gp = gt + ((size_t)b * M_ + m) * 4;
        x1 = fminf(bp[0], gp[0]); y1 = fminf(bp[1], gp[1]);
        x2 = fmaxf(bp[2], gp[2]); y2 = fmaxf(bp[3], gp[3]);
    }
    float rw = fmaxf(x2 - x1, 1.0f);
    float rh = fmaxf(y2 - y1, 1.0f);

    {   // y axis: windowed
        float bin = rh / 7.0f;
        float gf  = ceilf(bin);
        int   g   = (int)gf;
        float ivg = 1.0f / gf;
        float start = y1 + (float)p * bin;
        int base = (int)floorf(fmaxf(start, 0.0f));
        base = min(max(base, 0), H_ - 1);
        float* swp = &sw[threadIdx.x][0];
#pragma unroll
        for (int k = 0; k < K_; ++k) swp[k] = 0.0f;
        int len = 0;
        for (int s = 0; s < g; ++s) {
            float coord = start + ((float)s + 0.5f) * bin * ivg;
            if (coord < -1.0f || coord > (float)H_) continue;
            float cc = fmaxf(coord, 0.0f);
            int low = (int)floorf(cc);
            int high; float l;
            if (low >= H_ - 1) { low = H_ - 1; high = H_ - 1; l = 0.0f; }
            else               { high = low + 1; l = cc - (float)low; }
            int kl = min(max(low - base, 0), K_ - 1);
            int kh = min(max(high - base, 0), K_ - 1);
            swp[kl] += (1.0f - l) * ivg;
            swp[kh] += l * ivg;
            len = max(len, kh + 1);
        }
        float* wyp = ws_f + F_WY + (size_t)br * (P_ * K_) + p * K_;
#pragma unroll
        for (int k = 0; k < K_; ++k) wyp[k] = swp[k];
        ip[E_YB + br * P_ + p] = base;
        ip[E_YL + br * P_ + p] = len;
    }

    {   // x axis: dense transposed scatter
        float bin = rw / 7.0f;
        float gf  = ceilf(bin);
        int   g   = (int)gf;
        float ivg = 1.0f / gf;
        float start = x1 + (float)p * bin;
        float* axp = ws_f + F_AXD + (size_t)br * (W_ * P_);
        for (int s = 0; s < g; ++s) {
            float coord = start + ((float)s + 0.5f) * bin * ivg;
            if (coord < -1.0f || coord > (float)W_) continue;
            float cc = fmaxf(coord, 0.0f);
            int low = (int)floorf(cc);
            int high; float l;
            if (low >= W_ - 1) { low = W_ - 1; high = W_ - 1; l = 0.0f; }
            else               { high = low + 1; l = cc - (float)low; }
            atomicAdd(&axp[low * P_ + p],  (1.0f - l) * ivg);
            atomicAdd(&axp[high * P_ + p], l * ivg);
        }
        if (p == 0) {
            ip[E_XLO + br] = min(max((int)floorf(fmaxf(x1, 0.0f)), 0), W_ - 1);
            ip[E_XHI + br] = min(max((int)floorf(x1 + rw) + 1, 0), W_ - 1) + 1;
        }
    }
}

// ---------------------------------------------------------------------------
// Pass 2: block = (b, n, roi k), 256 threads = 4 waves = 4 channel-groups of
// the SAME roi (intra-block perfectly balanced; weights staged once for 4
// waves; LDS/block now buys 4 waves of residency -> ~28 waves/CU cap).
// Grid = 2*64*9 = 1152. Epilogue: 4 rounds through one shared lds_red,
// coalesced atomicAdd into d_out (zeroed each launch).
__global__ __launch_bounds__(256, 4) void k_main(const float* __restrict__ ws_f,
                                                 float* __restrict__ out) {
    __shared__ float lds_wy[P_ * K_];    //    336 B
    __shared__ float lds_ax[W_ * P_];    //  1,568 B
    __shared__ float lds_red[64 * 49];   // 12,544 B

    const int* ip = (const int*)ws_f;
    int bid  = blockIdx.x;
    int k    = bid % 9;
    int n    = (bid / 9) & (N_ - 1);
    int b    = bid / (9 * N_);
    int tid  = (int)threadIdx.x;
    int lane = tid & 63;
    int rg   = tid >> 6;                 // = channel group
    int c    = rg * 64 + lane;

    int r  = (k == 0) ? n : (N_ + n * M_ + (k - 1));
    int br = b * R_ + r;
    float scale = (k == 0) ? 1.0f : (1.0f / (float)M_);

    // stage this roi's weights into LDS (256 threads cooperative)
    if (tid < P_ * K_) lds_wy[tid] = ws_f[F_WY + (size_t)br * (P_ * K_) + tid];
    for (int j = tid; j < W_ * P_; j += 256)
        lds_ax[j] = ws_f[F_AXD + (size_t)br * (W_ * P_) + j];
    __syncthreads();

    int yb[P_], yl[P_];
#pragma unroll
    for (int py = 0; py < P_; ++py) {
        yb[py] = ip[E_YB + br * P_ + py];
        yl[py] = ip[E_YL + br * P_ + py];
    }
    int xlo = ip[E_XLO + br];
    int xhi = ip[E_XHI + br];

    const float* fmtb = ws_f + F_FMT + (size_t)b * (H_ * W_ * C_);

    float acc[49];
#pragma unroll
    for (int q = 0; q < 49; ++q) acc[q] = 0.0f;

    for (int x = xlo; x < xhi; x += 2) {
        bool two = (x + 1 < xhi);
        float cs0[P_], cs1[P_];
#pragma unroll
        for (int py = 0; py < P_; ++py) {
            float s0 = 0.0f, s1 = 0.0f;
            int off = (yb[py] * W_ + x) * C_ + c;
            int L = yl[py];
            for (int i = 0; i < L; ++i) {
                float wv = lds_wy[py * K_ + i];
                s0 = fmaf(wv, fmtb[off], s0);
                s1 = fmaf(wv, fmtb[off + C_], s1);   // x+1 col; stays in-ws
                off += W_ * C_;
            }
            cs0[py] = s0; cs1[py] = s1;
        }
#pragma unroll
        for (int px = 0; px < P_; ++px) {
            float w = lds_ax[x * P_ + px];
            if (w != 0.0f) {                          // wave-uniform branch
                w *= scale;
#pragma unroll
                for (int py = 0; py < P_; ++py)
                    acc[py * P_ + px] = fmaf(w, cs0[py], acc[py * P_ + px]);
            }
        }
        if (two) {
#pragma unroll
            for (int px = 0; px < P_; ++px) {
                float w = lds_ax[(x + 1) * P_ + px];
                if (w != 0.0f) {
                    w *= scale;
#pragma unroll
                    for (int py = 0; py < P_; ++py)
                        acc[py * P_ + px] = fmaf(w, cs1[py], acc[py * P_ + px]);
                }
            }
        }
    }

    // ---- epilogue: 4 rounds through shared lds_red, coalesced atomics ----
    float* outb = out + ((size_t)b * N_ + n) * (C_ * 49);
    __syncthreads();
#pragma unroll
    for (int w = 0; w < 4; ++w) {
        if (rg == w) {
#pragma unroll
            for (int q = 0; q < 49; ++q)
                lds_red[lane * 49 + q] = acc[q];      // 49 odd -> conflict-free
        }
        __syncthreads();
        float* outp = outb + w * 64 * 49;
        for (int e = tid; e < 64 * 49; e += 256)
            atomicAdd(&outp[e], lds_red[e]);
        __syncthreads();
    }
}

// ---------------------------------------------------------------------------
extern "C" void kernel_launch(void* const* d_in, const int* in_sizes, int n_in,
                              void* d_out, int out_size, void* d_ws, size_t ws_size,
                              hipStream_t stream) {
    const float* fm    = (const float*)d_in[0];
    const float* boxes = (const float*)d_in[1];
    const float* gt    = (const float*)d_in[2];
    float* ws_f = (float*)d_ws;
    float* out  = (float*)d_out;

    // axd is scatter-accumulated and out is atomic-accumulated -> zero both
    hipMemsetAsync(ws_f + F_AXD, 0, (size_t)N_AXD * sizeof(float), stream);
    hipMemsetAsync(out, 0, (size_t)out_size * sizeof(float), stream);
    k_transpose<<<B_ * H_ * 4, 64, 0, stream>>>(fm, ws_f + F_FMT);
    k_weights<<<(BR_ * P_ + 255) / 256, 256, 0, stream>>>(boxes, gt, ws_f);
    k_main<<<B_ * N_ * 9, 256, 0, stream>>>(ws_f, out);
}

// Round 4
// 270.107 us; speedup vs baseline: 1.7709x; 1.0474x over previous
//
#include <hip/hip_runtime.h>

#define B_ 2
#define C_ 256
#define H_ 56
#define W_ 56
#define N_ 64
#define M_ 8
#define P_ 7
#define R_ (N_ + N_*M_)          // 576 rois per image
#define BR_ (B_*R_)              // 1152
#define K_ 12                    // max y-window taps (bin<=7.92 -> support<=10)
#define SCTX_ 4                  // column chunks per ctx roi (box roi = 1)
#define JPN_ (1 + (M_)*SCTX_)    // 33 blocks per (b,n)

// ---- workspace layout (float-element offsets) ----
#define F_FMT 0
#define N_FMT (B_*H_*W_*C_)                  // 1,605,632  channel-last feature map
#define F_WY  (F_FMT + N_FMT)
#define N_WY  (BR_*P_*K_)                    // 96,768     windowed y-weights
#define F_AXD (F_WY + N_WY)
#define N_AXD (BR_*W_*P_)                    // 451,584    dense-in-x weights [x][px]
#define E_YB  (F_AXD + N_AXD)                // int region (aliased): ybase [BR][7]
#define E_YL  (E_YB + BR_*P_)                //                        ylen  [BR][7]
#define E_XLO (E_YL + BR_*P_)                //                        xlo   [BR]
#define E_XHI (E_XLO + BR_)                  //                        xhi   [BR]
#define WS_ELEMS (E_XHI + BR_)               // ~8.7 MB total

// ---------------------------------------------------------------------------
// Pass 0: fm[b][c][y][x] -> fmt[b][y][x][c]  (channel-last for coalesced lanes)
__global__ void k_transpose(const float* __restrict__ fm, float* __restrict__ fmt) {
    int bid = blockIdx.x;
    int cg  = bid & 3;
    int y   = (bid >> 2) % H_;
    int b   = bid / (4 * H_);
    int c   = cg * 64 + (int)threadIdx.x;
    const float4* src = (const float4*)(fm + (((size_t)b * C_ + c) * H_ + y) * W_);
    float* dst = fmt + ((size_t)b * H_ + y) * (size_t)(W_ * C_) + c;
#pragma unroll
    for (int x4 = 0; x4 < W_ / 4; ++x4) {
        float4 v = src[x4];
        dst[(x4 * 4 + 0) * C_] = v.x;
        dst[(x4 * 4 + 1) * C_] = v.y;
        dst[(x4 * 4 + 2) * C_] = v.z;
        dst[(x4 * 4 + 3) * C_] = v.w;
    }
}

// ---------------------------------------------------------------------------
// Pass 1: per-(b,roi,p) axis weights (unchanged — verified correct since R1).
__global__ void k_weights(const float* __restrict__ boxes,
                          const float* __restrict__ gt,
                          float* __restrict__ ws_f) {
    __shared__ float sw[256][K_];
    int tid = blockIdx.x * 256 + threadIdx.x;
    if (tid >= BR_ * P_) return;
    int p  = tid % P_;
    int br = tid / P_;
    int r  = br % R_;
    int b  = br / R_;
    int* ip = (int*)ws_f;

    float x1, y1, x2, y2;
    if (r < N_) {
        const float* bp = boxes + ((size_t)b * N_ + r) * 4;
        x1 = bp[0]; y1 = bp[1]; x2 = bp[2]; y2 = bp[3];
    } else {
        int q = r - N_;
        int n = q / M_, m = q % M_;
        const float* bp = boxes + ((size_t)b * N_ + n) * 4;
        const float* gp = gt + ((size_t)b * M_ + m) * 4;
        x1 = fminf(bp[0], gp[0]); y1 = fminf(bp[1], gp[1]);
        x2 = fmaxf(bp[2], gp[2]); y2 = fmaxf(bp[3], gp[3]);
    }
    float rw = fmaxf(x2 - x1, 1.0f);
    float rh = fmaxf(y2 - y1, 1.0f);

    {   // y axis: windowed
        float bin = rh / 7.0f;
        float gf  = ceilf(bin);
        int   g   = (int)gf;
        float ivg = 1.0f / gf;
        float start = y1 + (float)p * bin;
        int base = (int)floorf(fmaxf(start, 0.0f));
        base = min(max(base, 0), H_ - 1);
        float* swp = &sw[threadIdx.x][0];
#pragma unroll
        for (int k = 0; k < K_; ++k) swp[k] = 0.0f;
        int len = 0;
        for (int s = 0; s < g; ++s) {
            float coord = start + ((float)s + 0.5f) * bin * ivg;
            if (coord < -1.0f || coord > (float)H_) continue;
            float cc = fmaxf(coord, 0.0f);
            int low = (int)floorf(cc);
            int high; float l;
            if (low >= H_ - 1) { low = H_ - 1; high = H_ - 1; l = 0.0f; }
            else               { high = low + 1; l = cc - (float)low; }
            int kl = min(max(low - base, 0), K_ - 1);
            int kh = min(max(high - base, 0), K_ - 1);
            swp[kl] += (1.0f - l) * ivg;
            swp[kh] += l * ivg;
            len = max(len, kh + 1);
        }
        float* wyp = ws_f + F_WY + (size_t)br * (P_ * K_) + p * K_;
#pragma unroll
        for (int k = 0; k < K_; ++k) wyp[k] = swp[k];
        ip[E_YB + br * P_ + p] = base;
        ip[E_YL + br * P_ + p] = len;
    }

    {   // x axis: dense transposed scatter
        float bin = rw / 7.0f;
        float gf  = ceilf(bin);
        int   g   = (int)gf;
        float ivg = 1.0f / gf;
        float start = x1 + (float)p * bin;
        float* axp = ws_f + F_AXD + (size_t)br * (W_ * P_);
        for (int s = 0; s < g; ++s) {
            float coord = start + ((float)s + 0.5f) * bin * ivg;
            if (coord < -1.0f || coord > (float)W_) continue;
            float cc = fmaxf(coord, 0.0f);
            int low = (int)floorf(cc);
            int high; float l;
            if (low >= W_ - 1) { low = W_ - 1; high = W_ - 1; l = 0.0f; }
            else               { high = low + 1; l = cc - (float)low; }
            atomicAdd(&axp[low * P_ + p],  (1.0f - l) * ivg);
            atomicAdd(&axp[high * P_ + p], l * ivg);
        }
        if (p == 0) {
            ip[E_XLO + br] = min(max((int)floorf(fmaxf(x1, 0.0f)), 0), W_ - 1);
            ip[E_XHI + br] = min(max((int)floorf(x1 + rw) + 1, 0), W_ - 1) + 1;
        }
    }
}

// ---------------------------------------------------------------------------
// Pass 2: block = (b, n, j); j=0 -> box roi whole, j>0 -> ctx roi (j-1)/4,
// column-chunk (j-1)&3. 256 threads = 4 waves = 4 channel groups of the SAME
// work item -> uniform block durations, grid 4224 keeps all CUs queued.
// Epilogue: LDS transpose + coalesced atomicAdd into zeroed d_out.
__global__ __launch_bounds__(256, 4) void k_main(const float* __restrict__ ws_f,
                                                 float* __restrict__ out) {
    __shared__ float lds_wy[P_ * K_];    //    336 B
    __shared__ float lds_ax[W_ * P_];    //  1,568 B
    __shared__ float lds_red[64 * 49];   // 12,544 B

    const int* ip = (const int*)ws_f;
    int bid = blockIdx.x;
    int j   = bid % JPN_;
    int n   = (bid / JPN_) & (N_ - 1);
    int b   = bid / (JPN_ * N_);
    int k, s;
    if (j == 0) { k = 0; s = 0; }
    else        { k = 1 + ((j - 1) >> 2); s = (j - 1) & 3; }
    int tid  = (int)threadIdx.x;
    int lane = tid & 63;
    int rg   = tid >> 6;                 // channel group
    int c    = rg * 64 + lane;

    int r  = (k == 0) ? n : (N_ + n * M_ + (k - 1));
    int br = b * R_ + r;
    float scale = (k == 0) ? 1.0f : (1.0f / (float)M_);

    // column chunk for this block
    int xlo = ip[E_XLO + br];
    int xhi = ip[E_XHI + br];
    int xs, xe;
    if (k == 0) { xs = xlo; xe = xhi; }
    else {
        int cw = (xhi - xlo + SCTX_ - 1) >> 2;
        xs = xlo + s * cw;
        xe = min(xs + cw, xhi);
    }
    if (xs >= xe) return;                // uniform exit, before any barrier

    // stage this roi's weights into LDS (256 threads cooperative)
    if (tid < P_ * K_) lds_wy[tid] = ws_f[F_WY + (size_t)br * (P_ * K_) + tid];
    for (int jj = tid; jj < W_ * P_; jj += 256)
        lds_ax[jj] = ws_f[F_AXD + (size_t)br * (W_ * P_) + jj];
    __syncthreads();

    int yb[P_], yl[P_];
#pragma unroll
    for (int py = 0; py < P_; ++py) {
        yb[py] = ip[E_YB + br * P_ + py];
        yl[py] = ip[E_YL + br * P_ + py];
    }

    const float* fmtb = ws_f + F_FMT + (size_t)b * (H_ * W_ * C_);

    float acc[49];
#pragma unroll
    for (int q = 0; q < 49; ++q) acc[q] = 0.0f;

    for (int x = xs; x < xe; x += 2) {
        bool two = (x + 1 < xe);
        float cs0[P_], cs1[P_];
#pragma unroll
        for (int py = 0; py < P_; ++py) {
            float s0 = 0.0f, s1 = 0.0f;
            int off = (yb[py] * W_ + x) * C_ + c;
            int L = yl[py];
            for (int i = 0; i < L; ++i) {
                float wv = lds_wy[py * K_ + i];
                s0 = fmaf(wv, fmtb[off], s0);
                s1 = fmaf(wv, fmtb[off + C_], s1);   // x+1 col; stays in-ws
                off += W_ * C_;
            }
            cs0[py] = s0; cs1[py] = s1;
        }
#pragma unroll
        for (int px = 0; px < P_; ++px) {
            float w = lds_ax[x * P_ + px];
            if (w != 0.0f) {                          // wave-uniform branch
                w *= scale;
#pragma unroll
                for (int py = 0; py < P_; ++py)
                    acc[py * P_ + px] = fmaf(w, cs0[py], acc[py * P_ + px]);
            }
        }
        if (two) {
#pragma unroll
            for (int px = 0; px < P_; ++px) {
                float w = lds_ax[(x + 1) * P_ + px];
                if (w != 0.0f) {
                    w *= scale;
#pragma unroll
                    for (int py = 0; py < P_; ++py)
                        acc[py * P_ + px] = fmaf(w, cs1[py], acc[py * P_ + px]);
                }
            }
        }
    }

    // ---- epilogue: 4 rounds through shared lds_red, coalesced atomics ----
    float* outb = out + ((size_t)b * N_ + n) * (C_ * 49);
    __syncthreads();
#pragma unroll
    for (int w = 0; w < 4; ++w) {
        if (rg == w) {
#pragma unroll
            for (int q = 0; q < 49; ++q)
                lds_red[lane * 49 + q] = acc[q];      // 49 odd -> conflict-free
        }
        __syncthreads();
        float* outp = outb + w * 64 * 49;
        for (int e = tid; e < 64 * 49; e += 256)
            atomicAdd(&outp[e], lds_red[e]);
        __syncthreads();
    }
}

// ---------------------------------------------------------------------------
extern "C" void kernel_launch(void* const* d_in, const int* in_sizes, int n_in,
                              void* d_out, int out_size, void* d_ws, size_t ws_size,
                              hipStream_t stream) {
    const float* fm    = (const float*)d_in[0];
    const float* boxes = (const float*)d_in[1];
    const float* gt    = (const float*)d_in[2];
    float* ws_f = (float*)d_ws;
    float* out  = (float*)d_out;

    // axd is scatter-accumulated and out is atomic-accumulated -> zero both
    hipMemsetAsync(ws_f + F_AXD, 0, (size_t)N_AXD * sizeof(float), stream);
    hipMemsetAsync(out, 0, (size_t)out_size * sizeof(float), stream);
    k_transpose<<<B_ * H_ * 4, 64, 0, stream>>>(fm, ws_f + F_FMT);
    k_weights<<<(BR_ * P_ + 255) / 256, 256, 0, stream>>>(boxes, gt, ws_f);
    k_main<<<B_ * N_ * JPN_, 256, 0, stream>>>(ws_f, out);
}

// Round 5
// 204.055 us; speedup vs baseline: 2.3441x; 1.3237x over previous
//
#include <hip/hip_runtime.h>

#define B_ 2
#define C_ 256
#define H_ 56
#define W_ 56
#define N_ 64
#define M_ 8
#define P_ 7
#define R_ (N_ + N_*M_)          // 576 rois per image
#define BR_ (B_*R_)              // 1152
#define SCTX_ 4                  // column chunks per ctx roi (box roi = whole)
#define JPN_ (1 + (M_)*SCTX_)    // 33 blocks per (b,n)
#define WROW_ 8                  // padded weight-row stride (7 used + 1 pad)

// ---- workspace layout (float-element offsets) ----
#define F_FMT  0
#define N_FMT  (B_*H_*W_*C_)                 // channel-last feature map
#define F_WYD  (F_FMT + N_FMT)
#define N_WYD  (BR_*H_*WROW_)                // dense y-weights [y][py], stride 8
#define F_AXD  (F_WYD + N_WYD)
#define N_AXD  (BR_*W_*WROW_)                // dense x-weights [x][px], stride 8 (ctx pre-scaled 1/M)
#define F_OUTS (F_AXD + N_AXD)
#define N_OUTS (B_*N_*49*C_)                 // staging out [b][n][py][px][c]
#define E_XLO  (F_OUTS + N_OUTS)             // int region: xlo [BR]
#define E_XHI  (E_XLO + BR_)
#define E_YLO  (E_XHI + BR_)
#define E_YHI  (E_YLO + BR_)
#define WS_ELEMS (E_YHI + BR_)               // ~17 MB total

// ---------------------------------------------------------------------------
// Pass 0: fm[b][c][y][x] -> fmt[b][y][x][c]  (channel-last for coalesced lanes)
__global__ void k_transpose(const float* __restrict__ fm, float* __restrict__ fmt) {
    int bid = blockIdx.x;
    int cg  = bid & 3;
    int y   = (bid >> 2) % H_;
    int b   = bid / (4 * H_);
    int c   = cg * 64 + (int)threadIdx.x;
    const float4* src = (const float4*)(fm + (((size_t)b * C_ + c) * H_ + y) * W_);
    float* dst = fmt + ((size_t)b * H_ + y) * (size_t)(W_ * C_) + c;
#pragma unroll
    for (int x4 = 0; x4 < W_ / 4; ++x4) {
        float4 v = src[x4];
        dst[(x4 * 4 + 0) * C_] = v.x;
        dst[(x4 * 4 + 1) * C_] = v.y;
        dst[(x4 * 4 + 2) * C_] = v.z;
        dst[(x4 * 4 + 3) * C_] = v.w;
    }
}

// ---------------------------------------------------------------------------
// Pass 1: thread = (br, p). Dense weight columns, stride 8; threads with
// different p write disjoint dwords -> no atomics; each thread zeroes its own
// column first -> no memset needed. Ctx 1/M scale folded into axd.
__global__ void k_weights(const float* __restrict__ boxes,
                          const float* __restrict__ gt,
                          float* __restrict__ ws_f) {
    int tid = blockIdx.x * 256 + threadIdx.x;
    if (tid >= BR_ * P_) return;
    int p  = tid % P_;
    int br = tid / P_;
    int r  = br % R_;
    int b  = br / R_;
    int* ip = (int*)ws_f;

    float x1, y1, x2, y2;
    if (r < N_) {
        const float* bp = boxes + ((size_t)b * N_ + r) * 4;
        x1 = bp[0]; y1 = bp[1]; x2 = bp[2]; y2 = bp[3];
    } else {
        int q = r - N_;
        int n = q / M_, m = q % M_;
        const float* bp = boxes + ((size_t)b * N_ + n) * 4;
        const float* gp = gt + ((size_t)b * M_ + m) * 4;
        x1 = fminf(bp[0], gp[0]); y1 = fminf(bp[1], gp[1]);
        x2 = fmaxf(bp[2], gp[2]); y2 = fmaxf(bp[3], gp[3]);
    }
    float rw = fmaxf(x2 - x1, 1.0f);
    float rh = fmaxf(y2 - y1, 1.0f);

    {   // y axis, dense column p (weight 1.0)
        float bin = rh / 7.0f;
        float gf  = ceilf(bin);
        int   g   = (int)gf;
        float ivg = 1.0f / gf;
        float start = y1 + (float)p * bin;
        float* wcol = ws_f + F_WYD + (size_t)br * (H_ * WROW_) + p;
        for (int y = 0; y < H_; ++y) wcol[y * WROW_] = 0.0f;
        for (int s = 0; s < g; ++s) {
            float coord = start + ((float)s + 0.5f) * bin * ivg;
            if (coord < -1.0f || coord > (float)H_) continue;
            float cc = fmaxf(coord, 0.0f);
            int low = (int)floorf(cc);
            int high; float l;
            if (low >= H_ - 1) { low = H_ - 1; high = H_ - 1; l = 0.0f; }
            else               { high = low + 1; l = cc - (float)low; }
            wcol[low  * WROW_] += (1.0f - l) * ivg;
            wcol[high * WROW_] += l * ivg;
        }
    }

    {   // x axis, dense column p, ctx scale folded in
        float bin = rw / 7.0f;
        float gf  = ceilf(bin);
        int   g   = (int)gf;
        float ivg = 1.0f / gf;
        float fs  = (r < N_) ? ivg : ivg * (1.0f / (float)M_);
        float start = x1 + (float)p * bin;
        float* acol = ws_f + F_AXD + (size_t)br * (W_ * WROW_) + p;
        for (int x = 0; x < W_; ++x) acol[x * WROW_] = 0.0f;
        for (int s = 0; s < g; ++s) {
            float coord = start + ((float)s + 0.5f) * bin * ivg;
            if (coord < -1.0f || coord > (float)W_) continue;
            float cc = fmaxf(coord, 0.0f);
            int low = (int)floorf(cc);
            int high; float l;
            if (low >= W_ - 1) { low = W_ - 1; high = W_ - 1; l = 0.0f; }
            else               { high = low + 1; l = cc - (float)low; }
            acol[low  * WROW_] += (1.0f - l) * fs;
            acol[high * WROW_] += l * fs;
        }
        if (p == 0) {
            ip[E_XLO + br] = min(max((int)floorf(fmaxf(x1, 0.0f)), 0), W_ - 1);
            ip[E_XHI + br] = min(max((int)floorf(x1 + rw) + 1, 0), W_ - 1) + 1;
            ip[E_YLO + br] = min(max((int)floorf(fmaxf(y1, 0.0f)), 0), H_ - 1);
            ip[E_YHI + br] = min(max((int)floorf(y1 + rh) + 1, 0), H_ - 1) + 1;
        }
    }
}

// ---------------------------------------------------------------------------
// Pass 2: block = (b, n, j); 256 thr = 4 waves = 4 channel groups, same work
// item (uniform durations). Dense-y inner loop: 2 independent loads feed 14
// unrolled FMAs; weights read via wave-uniform (scalarizable) global loads.
// No LDS. Epilogue: live-px coalesced atomics into outS [py][px][c].
__global__ __launch_bounds__(256, 5) void k_main(const float* __restrict__ ws_f,
                                                 float* __restrict__ outs) {
    const int* ip = (const int*)ws_f;
    int bid = blockIdx.x;
    int j   = bid % JPN_;
    int n   = (bid / JPN_) & (N_ - 1);
    int b   = bid / (JPN_ * N_);
    int k, s;
    if (j == 0) { k = 0; s = 0; }
    else        { k = 1 + ((j - 1) >> 2); s = (j - 1) & 3; }
    int tid  = (int)threadIdx.x;
    int lane = tid & 63;
    int rg   = tid >> 6;
    int c    = rg * 64 + lane;

    int r  = (k == 0) ? n : (N_ + n * M_ + (k - 1));
    int br = b * R_ + r;

    int xlo = ip[E_XLO + br];
    int xhi = ip[E_XHI + br];
    int ylo = ip[E_YLO + br];
    int yhi = ip[E_YHI + br];
    int xs, xe;
    if (k == 0) { xs = xlo; xe = xhi; }
    else {
        int cw = (xhi - xlo + SCTX_ - 1) >> 2;
        xs = xlo + s * cw;
        xe = min(xs + cw, xhi);
    }
    if (xs >= xe) return;

    const float* wyd  = ws_f + F_WYD + (size_t)br * (H_ * WROW_);
    const float* axd  = ws_f + F_AXD + (size_t)br * (W_ * WROW_);
    const float* fmtb = ws_f + F_FMT + (size_t)b * (H_ * W_ * C_);

    float acc[49];
#pragma unroll
    for (int q = 0; q < 49; ++q) acc[q] = 0.0f;
    int live = 0;

    for (int x = xs; x < xe; x += 2) {
        bool two = (x + 1 < xe);
        float cs0[P_], cs1[P_];
#pragma unroll
        for (int py = 0; py < P_; ++py) { cs0[py] = 0.0f; cs1[py] = 0.0f; }

        const float* col = fmtb + ((size_t)(ylo * W_ + x)) * C_ + c;
        for (int y = ylo; y < yhi; ++y) {
            float v0 = col[0];
            float v1 = col[C_];            // x+1 (or discard); stays in-ws
            const float* wr = wyd + y * WROW_;   // wave-uniform -> s_load
#pragma unroll
            for (int py = 0; py < P_; ++py) {
                float w = wr[py];
                cs0[py] = fmaf(w, v0, cs0[py]);
                cs1[py] = fmaf(w, v1, cs1[py]);
            }
            col += W_ * C_;
        }

        const float* ar = axd + x * WROW_;       // wave-uniform
#pragma unroll
        for (int px = 0; px < P_; ++px) {
            float w = ar[px];
            if (w != 0.0f) {                     // wave-uniform branch
                live |= 1 << px;
#pragma unroll
                for (int py = 0; py < P_; ++py)
                    acc[py * P_ + px] = fmaf(w, cs0[py], acc[py * P_ + px]);
            }
        }
        if (two) {
#pragma unroll
            for (int px = 0; px < P_; ++px) {
                float w = ar[WROW_ + px];
                if (w != 0.0f) {
                    live |= 1 << px;
#pragma unroll
                    for (int py = 0; py < P_; ++py)
                        acc[py * P_ + px] = fmaf(w, cs1[py], acc[py * P_ + px]);
                }
            }
        }
    }

    // ---- epilogue: coalesced wave-atomics, live px columns only ----
    float* os = outs + ((size_t)b * N_ + n) * (49 * C_) + c;
#pragma unroll
    for (int px = 0; px < P_; ++px) {
        if (live & (1 << px)) {
#pragma unroll
            for (int py = 0; py < P_; ++py)
                atomicAdd(os + (py * P_ + px) * C_, acc[py * P_ + px]);
        }
    }
}

// ---------------------------------------------------------------------------
// Pass 3: outS [b][n][py][px][c] -> out [b][n][c][py][px] via padded LDS tile.
__global__ __launch_bounds__(256) void k_final(const float* __restrict__ outs,
                                               float* __restrict__ out) {
    __shared__ float t[49 * 257];        // pad 257: transpose-read conflict-free
    int bn  = blockIdx.x;                // 0..B*N-1
    int tid = (int)threadIdx.x;
    const float* src = outs + (size_t)bn * (49 * C_);
    for (int e = tid; e < 49 * C_; e += 256) {
        int q = e >> 8, c = e & 255;
        t[q * 257 + c] = src[e];         // coalesced read
    }
    __syncthreads();
    float* dst = out + (size_t)bn * (C_ * 49);
    for (int e = tid; e < C_ * 49; e += 256) {
        int c = e / 49, q = e % 49;
        dst[e] = t[q * 257 + c];         // coalesced write, stride-257 LDS read
    }
}

// ---------------------------------------------------------------------------
extern "C" void kernel_launch(void* const* d_in, const int* in_sizes, int n_in,
                              void* d_out, int out_size, void* d_ws, size_t ws_size,
                              hipStream_t stream) {
    const float* fm    = (const float*)d_in[0];
    const float* boxes = (const float*)d_in[1];
    const float* gt    = (const float*)d_in[2];
    float* ws_f = (float*)d_ws;
    float* out  = (float*)d_out;
    float* outs = ws_f + F_OUTS;

    hipMemsetAsync(outs, 0, (size_t)N_OUTS * sizeof(float), stream);
    k_transpose<<<B_ * H_ * 4, 64, 0, stream>>>(fm, ws_f + F_FMT);
    k_weights<<<(BR_ * P_ + 255) / 256, 256, 0, stream>>>(boxes, gt, ws_f);
    k_main<<<B_ * N_ * JPN_, 256, 0, stream>>>(ws_f, outs);
    k_final<<<B_ * N_, 256, 0, stream>>>(outs, out);
}

// Round 6
// 172.703 us; speedup vs baseline: 2.7697x; 1.1815x over previous
//
#include <hip/hip_runtime.h>

#define B_ 2
#define C_ 256
#define H_ 56
#define W_ 56
#define N_ 64
#define M_ 8
#define P_ 7
#define R_ (N_ + N_*M_)          // 576 rois per image
#define BR_ (B_*R_)              // 1152
#define SCTX_ 4                  // column chunks per ctx roi (box roi = whole)
#define JPN_ (1 + (M_)*SCTX_)    // 33 blocks per (b,n)
#define WROW_ 8                  // padded weight-row stride (7 used + 1 pad)

// ---- workspace layout (float-element offsets) ----
#define F_FMT  0
#define N_FMT  (B_*H_*W_*C_)                 // channel-last feature map
#define F_WYD  (F_FMT + N_FMT)
#define N_WYD  (BR_*H_*WROW_)                // dense y-weights [y][py], stride 8
#define F_AXD  (F_WYD + N_WYD)
#define N_AXD  (BR_*W_*WROW_)                // dense x-weights [x][px] (ctx pre-scaled 1/M)
#define F_OUTS (F_AXD + N_AXD)
#define N_OUTS (B_*N_*49*C_)                 // staging out [b][n][py][px][c]
#define E_XLO  (F_OUTS + N_OUTS)             // int region
#define E_XHI  (E_XLO + BR_)
#define E_YLO  (E_XHI + BR_)
#define E_YHI  (E_YLO + BR_)
#define WS_ELEMS (E_YHI + BR_)               // ~17 MB total

// fused prep kernel block ranges
#define PREP_T 112                           // transpose: B*H blocks
#define PREP_W (PREP_T + 32)                 // weights: 8192 threads
#define PREP_Z (PREP_W + 784)                // zero outS: 784*2048 floats

// ---------------------------------------------------------------------------
// k_prep: three jobs in one dispatch (mutually independent, all pre-k_main).
//   [0,112):   fm[b][c][y][x] -> fmt[b][y][x][c]
//   [112,144): per-(br,p) dense axis weights (verified math since R5)
//   [144,928): zero outS
__global__ __launch_bounds__(256) void k_prep(const float* __restrict__ fm,
                                              const float* __restrict__ boxes,
                                              const float* __restrict__ gt,
                                              float* __restrict__ ws_f) {
    int bid = blockIdx.x;
    int tid = (int)threadIdx.x;

    if (bid < PREP_T) {                      // ---- transpose ----
        int y = bid % H_, b = bid / H_;
        int c = tid;                         // all 256 channels
        const float4* src = (const float4*)(fm + (((size_t)b * C_ + c) * H_ + y) * W_);
        float* dst = ws_f + F_FMT + ((size_t)b * H_ + y) * (size_t)(W_ * C_) + c;
#pragma unroll
        for (int x4 = 0; x4 < W_ / 4; ++x4) {
            float4 v = src[x4];
            dst[(x4 * 4 + 0) * C_] = v.x;
            dst[(x4 * 4 + 1) * C_] = v.y;
            dst[(x4 * 4 + 2) * C_] = v.z;
            dst[(x4 * 4 + 3) * C_] = v.w;
        }
        return;
    }

    if (bid < PREP_W) {                      // ---- weights ----
        int t = (bid - PREP_T) * 256 + tid;
        if (t >= BR_ * P_) return;
        int p  = t % P_;
        int br = t / P_;
        int r  = br % R_;
        int b  = br / R_;
        int* ip = (int*)ws_f;

        float x1, y1, x2, y2;
        if (r < N_) {
            const float* bp = boxes + ((size_t)b * N_ + r) * 4;
            x1 = bp[0]; y1 = bp[1]; x2 = bp[2]; y2 = bp[3];
        } else {
            int q = r - N_;
            int n = q / M_, m = q % M_;
            const float* bp = boxes + ((size_t)b * N_ + n) * 4;
            const float* gp = gt + ((size_t)b * M_ + m) * 4;
            x1 = fminf(bp[0], gp[0]); y1 = fminf(bp[1], gp[1]);
            x2 = fmaxf(bp[2], gp[2]); y2 = fmaxf(bp[3], gp[3]);
        }
        float rw = fmaxf(x2 - x1, 1.0f);
        float rh = fmaxf(y2 - y1, 1.0f);

        {   // y axis, dense column p
            float bin = rh / 7.0f;
            float gf  = ceilf(bin);
            int   g   = (int)gf;
            float ivg = 1.0f / gf;
            float start = y1 + (float)p * bin;
            float* wcol = ws_f + F_WYD + (size_t)br * (H_ * WROW_) + p;
            for (int y = 0; y < H_; ++y) wcol[y * WROW_] = 0.0f;
            for (int s = 0; s < g; ++s) {
                float coord = start + ((float)s + 0.5f) * bin * ivg;
                if (coord < -1.0f || coord > (float)H_) continue;
                float cc = fmaxf(coord, 0.0f);
                int low = (int)floorf(cc);
                int high; float l;
                if (low >= H_ - 1) { low = H_ - 1; high = H_ - 1; l = 0.0f; }
                else               { high = low + 1; l = cc - (float)low; }
                wcol[low  * WROW_] += (1.0f - l) * ivg;
                wcol[high * WROW_] += l * ivg;
            }
        }
        {   // x axis, dense column p, ctx 1/M folded in
            float bin = rw / 7.0f;
            float gf  = ceilf(bin);
            int   g   = (int)gf;
            float ivg = 1.0f / gf;
            float fs  = (r < N_) ? ivg : ivg * (1.0f / (float)M_);
            float start = x1 + (float)p * bin;
            float* acol = ws_f + F_AXD + (size_t)br * (W_ * WROW_) + p;
            for (int x = 0; x < W_; ++x) acol[x * WROW_] = 0.0f;
            for (int s = 0; s < g; ++s) {
                float coord = start + ((float)s + 0.5f) * bin * ivg;
                if (coord < -1.0f || coord > (float)W_) continue;
                float cc = fmaxf(coord, 0.0f);
                int low = (int)floorf(cc);
                int high; float l;
                if (low >= W_ - 1) { low = W_ - 1; high = W_ - 1; l = 0.0f; }
                else               { high = low + 1; l = cc - (float)low; }
                acol[low  * WROW_] += (1.0f - l) * fs;
                acol[high * WROW_] += l * fs;
            }
            if (p == 0) {
                ip[E_XLO + br] = min(max((int)floorf(fmaxf(x1, 0.0f)), 0), W_ - 1);
                ip[E_XHI + br] = min(max((int)floorf(x1 + rw) + 1, 0), W_ - 1) + 1;
                ip[E_YLO + br] = min(max((int)floorf(fmaxf(y1, 0.0f)), 0), H_ - 1);
                ip[E_YHI + br] = min(max((int)floorf(y1 + rh) + 1, 0), H_ - 1) + 1;
            }
        }
        return;
    }

    {                                        // ---- zero outS ----
        int t = (bid - PREP_W) * 256 + tid;  // < 200,704
        float4 z = {0.0f, 0.0f, 0.0f, 0.0f};
        float4* dst = (float4*)(ws_f + F_OUTS);
        dst[t * 2]     = z;
        dst[t * 2 + 1] = z;
    }
}

// ---------------------------------------------------------------------------
// k_main: block = (b, n, j); 256 thr = 4 waves = 4 channel groups, same work
// item. Inner loop: x-QUAD x y-PAIR -> 8 independent global loads feed 56
// unrolled FMAs (per-wave MLP 4x vs R5). Weights via wave-uniform s_loads.
// No LDS. Epilogue: live-px coalesced atomics into outS [py][px][c].
// launch_bounds(256,4): 128-reg unified budget fits cs[28]+vals[8]+acc[49
// in AGPR] without scratch spill ((256,5)'s 102 cap would spill).
__global__ __launch_bounds__(256, 4) void k_main(const float* __restrict__ ws_f,
                                                 float* __restrict__ outs) {
    const int* ip = (const int*)ws_f;
    int bid = blockIdx.x;
    int j   = bid % JPN_;
    int n   = (bid / JPN_) & (N_ - 1);
    int b   = bid / (JPN_ * N_);
    int k, s;
    if (j == 0) { k = 0; s = 0; }
    else        { k = 1 + ((j - 1) >> 2); s = (j - 1) & 3; }
    int tid  = (int)threadIdx.x;
    int lane = tid & 63;
    int rg   = tid >> 6;
    int c    = rg * 64 + lane;

    int r  = (k == 0) ? n : (N_ + n * M_ + (k - 1));
    int br = b * R_ + r;

    int xlo = ip[E_XLO + br];
    int xhi = ip[E_XHI + br];
    int ylo = ip[E_YLO + br];
    int yhi = ip[E_YHI + br];
    int xs, xe;
    if (k == 0) { xs = xlo; xe = xhi; }
    else {
        int cw = (xhi - xlo + SCTX_ - 1) >> 2;
        xs = xlo + s * cw;
        xe = min(xs + cw, xhi);
    }
    if (xs >= xe) return;

    const float* wyd  = ws_f + F_WYD + (size_t)br * (H_ * WROW_);
    const float* axd  = ws_f + F_AXD + (size_t)br * (W_ * WROW_);
    const float* fmtb = ws_f + F_FMT + (size_t)b * (H_ * W_ * C_);

    float acc[49];
#pragma unroll
    for (int q = 0; q < 49; ++q) acc[q] = 0.0f;
    int live = 0;

    for (int x = xs; x < xe; x += 4) {
        float cs[4][P_];
#pragma unroll
        for (int i = 0; i < 4; ++i)
#pragma unroll
            for (int py = 0; py < P_; ++py) cs[i][py] = 0.0f;

        // over-read x+1..x+3 past xe/roi edge is harmless: addresses stay
        // inside d_ws (worst case lands in F_WYD region), values unused.
        const float* col = fmtb + ((size_t)(ylo * W_ + x)) * C_ + c;
        int y = ylo;
        for (; y + 2 <= yhi; y += 2) {
            float a0 = col[0];
            float a1 = col[C_];
            float a2 = col[2 * C_];
            float a3 = col[3 * C_];
            float b0 = col[W_ * C_];
            float b1 = col[W_ * C_ + C_];
            float b2 = col[W_ * C_ + 2 * C_];
            float b3 = col[W_ * C_ + 3 * C_];
            const float* w0 = wyd + y * WROW_;        // wave-uniform -> s_load
            const float* w1 = w0 + WROW_;
#pragma unroll
            for (int py = 0; py < P_; ++py) {
                float u0 = w0[py], u1 = w1[py];
                cs[0][py] = fmaf(u1, b0, fmaf(u0, a0, cs[0][py]));
                cs[1][py] = fmaf(u1, b1, fmaf(u0, a1, cs[1][py]));
                cs[2][py] = fmaf(u1, b2, fmaf(u0, a2, cs[2][py]));
                cs[3][py] = fmaf(u1, b3, fmaf(u0, a3, cs[3][py]));
            }
            col += 2 * W_ * C_;
        }
        if (y < yhi) {                                // odd tail row
            float a0 = col[0];
            float a1 = col[C_];
            float a2 = col[2 * C_];
            float a3 = col[3 * C_];
            const float* w0 = wyd + y * WROW_;
#pragma unroll
            for (int py = 0; py < P_; ++py) {
                float u0 = w0[py];
                cs[0][py] = fmaf(u0, a0, cs[0][py]);
                cs[1][py] = fmaf(u0, a1, cs[1][py]);
                cs[2][py] = fmaf(u0, a2, cs[2][py]);
                cs[3][py] = fmaf(u0, a3, cs[3][py]);
            }
        }

        const float* ar = axd + x * WROW_;            // wave-uniform
#pragma unroll
        for (int i = 0; i < 4; ++i) {
            if (x + i < xe) {                         // wave-uniform branch
#pragma unroll
                for (int px = 0; px < P_; ++px) {
                    float w = ar[i * WROW_ + px];
                    if (w != 0.0f) {
                        live |= 1 << px;
#pragma unroll
                        for (int py = 0; py < P_; ++py)
                            acc[py * P_ + px] = fmaf(w, cs[i][py], acc[py * P_ + px]);
                    }
                }
            }
        }
    }

    // ---- epilogue: coalesced wave-atomics, live px columns only ----
    float* os = outs + ((size_t)b * N_ + n) * (49 * C_) + c;
#pragma unroll
    for (int px = 0; px < P_; ++px) {
        if (live & (1 << px)) {
#pragma unroll
            for (int py = 0; py < P_; ++py)
                atomicAdd(os + (py * P_ + px) * C_, acc[py * P_ + px]);
        }
    }
}

// ---------------------------------------------------------------------------
// k_final: outS [b][n][py][px][c] -> out [b][n][c][py][px] via padded LDS.
__global__ __launch_bounds__(256) void k_final(const float* __restrict__ outs,
                                               float* __restrict__ out) {
    __shared__ float t[49 * 257];        // pad 257: conflict-free transpose read
    int bn  = blockIdx.x;                // 0..B*N-1
    int tid = (int)threadIdx.x;
    const float* src = outs + (size_t)bn * (49 * C_);
    for (int e = tid; e < 49 * C_; e += 256) {
        int q = e >> 8, c = e & 255;
        t[q * 257 + c] = src[e];         // coalesced read
    }
    __syncthreads();
    float* dst = out + (size_t)bn * (C_ * 49);
    for (int e = tid; e < C_ * 49; e += 256) {
        int c = e / 49, q = e % 49;
        dst[e] = t[q * 257 + c];         // coalesced write
    }
}

// ---------------------------------------------------------------------------
extern "C" void kernel_launch(void* const* d_in, const int* in_sizes, int n_in,
                              void* d_out, int out_size, void* d_ws, size_t ws_size,
                              hipStream_t stream) {
    const float* fm    = (const float*)d_in[0];
    const float* boxes = (const float*)d_in[1];
    const float* gt    = (const float*)d_in[2];
    float* ws_f = (float*)d_ws;
    float* out  = (float*)d_out;
    float* outs = ws_f + F_OUTS;

    k_prep<<<PREP_Z, 256, 0, stream>>>(fm, boxes, gt, ws_f);
    k_main<<<B_ * N_ * JPN_, 256, 0, stream>>>(ws_f, outs);
    k_final<<<B_ * N_, 256, 0, stream>>>(outs, out);
}